// Round 5
// baseline (780.851 us; speedup 1.0000x reference)
//
#include <hip/hip_runtime.h>
#include <stdint.h>

// ---------- bf16 helpers (OCP bf16 == high 16 bits of f32) ----------
__device__ __forceinline__ float bf2f(unsigned short h) {
  union { uint32_t u; float f; } v; v.u = ((uint32_t)h) << 16; return v.f;
}
__device__ __forceinline__ unsigned short f2bf(float f) {
  union { float f; uint32_t u; } v; v.f = f;
  uint32_t u = v.u;
  u += 0x7FFFu + ((u >> 16) & 1u);   // round-to-nearest-even
  return (unsigned short)(u >> 16);
}
__device__ __forceinline__ uint32_t pack2bf(float a, float b) {
  return (uint32_t)f2bf(a) | ((uint32_t)f2bf(b) << 16);
}

typedef __attribute__((ext_vector_type(8))) short short8;   // 8 bf16 (4 VGPRs)
typedef __attribute__((ext_vector_type(4))) float floatx4;  // MFMA C/D

// async global->LDS, 16 B/lane. LDS dest = wave-uniform base + lane*16 (m104/m108).
__device__ __forceinline__ void gl2lds16(const unsigned short* g, unsigned short* l) {
  __builtin_amdgcn_global_load_lds(
      (const __attribute__((address_space(1))) uint32_t*)(const void*)g,
      (__attribute__((address_space(3))) uint32_t*)(void*)l,
      16, 0, 0);
}

// ---------- dtype probe ----------
// flags[0] = 1 if float inputs are fp32 (else bf16); flags[1] = 1 if edge_index int64
__global__ void bgcn_probe(const uint32_t* __restrict__ xw,
                           const uint32_t* __restrict__ iw,
                           int* __restrict__ flags) {
  if (threadIdx.x == 0 && blockIdx.x == 0) {
    int hits = 0;
    for (int i = 0; i < 256; ++i) {
      uint32_t b = (xw[i] >> 8) & 0x7F;
      if (b >= 0x38 && b <= 0x41) hits++;
    }
    flags[0] = (hits < 128) ? 1 : 0;
    int nz = 0;
    for (int i = 1; i < 128; i += 2) nz += (iw[i] != 0);
    flags[1] = (nz == 0) ? 1 : 0;
  }
}

// ---------- canonicalization ----------
__global__ void bgcn_cvt_f(const void* __restrict__ src, unsigned short* __restrict__ dst,
                           int n, const int* __restrict__ flags) {
  int i = blockIdx.x * 256 + threadIdx.x;
  if (i >= n) return;
  if (flags[0]) dst[i] = f2bf(((const float*)src)[i]);
  else          dst[i] = ((const unsigned short*)src)[i];
}
// vectorized 8-elem/thread cvt (X pre-pass)
__global__ void bgcn_cvt8(const void* __restrict__ src, unsigned short* __restrict__ dst,
                          int n8, const int* __restrict__ flags) {
  int i = blockIdx.x * 256 + threadIdx.x;
  if (i >= n8) return;
  size_t o = (size_t)i * 8;
  uint4 d;
  if (flags[0]) {
    const float4* f = (const float4*)((const float*)src + o);
    float4 f0 = f[0], f1 = f[1];
    d = make_uint4(pack2bf(f0.x, f0.y), pack2bf(f0.z, f0.w),
                   pack2bf(f1.x, f1.y), pack2bf(f1.z, f1.w));
  } else {
    d = *(const uint4*)((const unsigned short*)src + o);
  }
  *(uint4*)(dst + o) = d;
}
__global__ void bgcn_cvt_i(const void* __restrict__ src, int* __restrict__ dst,
                           int n, const int* __restrict__ flags) {
  int i = blockIdx.x * 256 + threadIdx.x;
  if (i >= n) return;
  if (flags[1]) dst[i] = (int)((const long long*)src)[i];
  else          dst[i] = ((const int*)src)[i];
}
// transpose + cvt: dst[N][K] bf16 <- src[K][N] (fp32 or bf16). K = 1<<kbits.
__global__ void bgcn_cvt_t(const void* __restrict__ src, unsigned short* __restrict__ dst,
                           int kbits, int N, int total, const int* __restrict__ flags) {
  int i = blockIdx.x * 256 + threadIdx.x;
  if (i >= total) return;
  int K = 1 << kbits;
  int n = i >> kbits;
  int k = i & (K - 1);
  size_t s = (size_t)k * N + n;
  if (flags[0]) dst[i] = f2bf(((const float*)src)[s]);
  else          dst[i] = ((const unsigned short*)src)[s];
}

// ---------- degree / normalization ----------
__global__ void bgcn_init_deg(float* __restrict__ deg, int n) {
  int i = blockIdx.x * 256 + threadIdx.x;
  if (i < n) deg[i] = 1.0f;
}
__global__ void bgcn_deg(const int* __restrict__ col, const unsigned short* __restrict__ ew,
                         float* __restrict__ deg, int E) {
  int e = blockIdx.x * 256 + threadIdx.x;
  if (e < E) atomicAdd(&deg[col[e]], bf2f(ew[e]));
}
__global__ void bgcn_dis(const float* __restrict__ deg, float* __restrict__ dis, int n) {
  int i = blockIdx.x * 256 + threadIdx.x;
  if (i < n) dis[i] = rsqrtf(deg[i]);
}

// ---------- CSR build ----------
__global__ void bgcn_hist(const int* __restrict__ col, int* __restrict__ counts, int E) {
  int e = blockIdx.x * 256 + threadIdx.x;
  if (e < E) atomicAdd(&counts[col[e]], 1);
}
__global__ void bgcn_scan_block(const int* __restrict__ counts, int* __restrict__ rowptr,
                                int* __restrict__ blocksum, int n) {
  __shared__ int buf[1024];
  int gid = blockIdx.x * 1024 + threadIdx.x;
  int v = (gid < n) ? counts[gid] : 0;
  buf[threadIdx.x] = v;
  __syncthreads();
  for (int off = 1; off < 1024; off <<= 1) {
    int x = (threadIdx.x >= off) ? buf[threadIdx.x - off] : 0;
    __syncthreads();
    buf[threadIdx.x] += x;
    __syncthreads();
  }
  if (gid < n) rowptr[gid + 1] = buf[threadIdx.x];
  if (threadIdx.x == 1023) blocksum[blockIdx.x] = buf[1023];
}
__global__ void bgcn_scan_tops(int* __restrict__ blocksum, int nb) {
  if (threadIdx.x == 0 && blockIdx.x == 0) {
    int acc = 0;
    for (int i = 0; i < nb; ++i) { int v = blocksum[i]; blocksum[i] = acc; acc += v; }
  }
}
__global__ void bgcn_scan_add(int* __restrict__ rowptr, const int* __restrict__ blocksum, int n) {
  int gid = blockIdx.x * 1024 + threadIdx.x;
  if (gid < n) rowptr[gid + 1] += blocksum[blockIdx.x];
  if (gid == 0) rowptr[0] = 0;
}
__global__ void bgcn_scatter(const int* __restrict__ row, const int* __restrict__ col,
                             const unsigned short* __restrict__ ew,
                             const float* __restrict__ dis,
                             const int* __restrict__ rowptr, int* __restrict__ fill,
                             int* __restrict__ esrc, float* __restrict__ enorm, int E) {
  int e = blockIdx.x * 256 + threadIdx.x;
  if (e >= E) return;
  int r = row[e], c = col[e];
  int pos = rowptr[c] + atomicAdd(&fill[c], 1);
  esrc[pos]  = r;
  enorm[pos] = dis[r] * bf2f(ew[e]) * dis[c];
}

// ---------- m97-style MFMA GEMM (bf16 A): C[MxN] = A[MxK] @ Bt[NxK]^T ----------
// 256 thr = 4 waves; 128x128 tile, BK=32; global_load_lds 16B staging.
// LDS layout UNPADDED stride 32 shorts (64 B) -- required: DMA writes
// wave-uniform base + lane*16B. Wave w stages rows [w*32, w*32+32) of A and B
// (2 issues of 16 rows each). Bank conflicts on ds_read_b128 are the m98-style
// tolerable ones.
__global__ __launch_bounds__(256) void bgcn_gemm_lds(
    const unsigned short* __restrict__ A,
    const unsigned short* __restrict__ Bt,
    unsigned short* __restrict__ C,
    int M, int N, int K, int nblk_bits) {
  __shared__ unsigned short Abuf[128 * 32];
  __shared__ unsigned short Bbuf[128 * 32];
  int t = threadIdx.x;
  int wave = t >> 6, lane = t & 63;
  int bx = blockIdx.x;
  int nblk = bx & ((1 << nblk_bits) - 1);
  int mblk = bx >> nblk_bits;
  int m0 = mblk * 128, n0 = nblk * 128;

  floatx4 acc[4][4];
  #pragma unroll
  for (int i = 0; i < 4; ++i)
    #pragma unroll
    for (int j = 0; j < 4; ++j)
      #pragma unroll
      for (int r = 0; r < 4; ++r) acc[i][j][r] = 0.0f;

  // staging addresses: lane l -> row (l>>2) within 16-row issue, k-chunk (l&3)*8
  int rii  = lane >> 2;
  int koff = (lane & 3) * 8;
  int ar0 = m0 + wave * 32 + rii;      if (ar0 >= M) ar0 = M - 1;  // clamp, masked at store
  int ar1 = m0 + wave * 32 + 16 + rii; if (ar1 >= M) ar1 = M - 1;
  const unsigned short* Ag0 = A + (size_t)ar0 * K + koff;
  const unsigned short* Ag1 = A + (size_t)ar1 * K + koff;
  const unsigned short* Bg0 = Bt + (size_t)(n0 + wave * 32 + rii) * K + koff;
  const unsigned short* Bg1 = Bg0 + (size_t)16 * K;
  // per-lane LDS ptr consistent with base + lane*16B
  unsigned short* Al0 = Abuf + (wave * 32) * 32 + lane * 8;
  unsigned short* Al1 = Abuf + (wave * 32 + 16) * 32 + lane * 8;
  unsigned short* Bl0 = Bbuf + (wave * 32) * 32 + lane * 8;
  unsigned short* Bl1 = Bbuf + (wave * 32 + 16) * 32 + lane * 8;

  int fr = lane & 15;           // row within 16-tile
  int fk = (lane >> 4) * 8;     // k offset of this quad
  int mw = (wave & 1) * 64;     // wave's 64x64 sub-tile
  int nw = (wave >> 1) * 64;

  for (int k0 = 0; k0 < K; k0 += 32) {
    gl2lds16(Ag0 + k0, Al0);
    gl2lds16(Ag1 + k0, Al1);
    gl2lds16(Bg0 + k0, Bl0);
    gl2lds16(Bg1 + k0, Bl1);
    __syncthreads();

    short8 afr[4], bfr[4];
    #pragma unroll
    for (int i = 0; i < 4; ++i)
      afr[i] = *(const short8*)(Abuf + (mw + i * 16 + fr) * 32 + fk);
    #pragma unroll
    for (int i = 0; i < 4; ++i)
      bfr[i] = *(const short8*)(Bbuf + (nw + i * 16 + fr) * 32 + fk);
    #pragma unroll
    for (int mt = 0; mt < 4; ++mt)
      #pragma unroll
      for (int nt = 0; nt < 4; ++nt)
        acc[mt][nt] = __builtin_amdgcn_mfma_f32_16x16x32_bf16(afr[mt], bfr[nt], acc[mt][nt], 0, 0, 0);
    __syncthreads();
  }

  // D: col=lane&15, row=(lane>>4)*4+r  [m89-verified]
  int col_l = lane & 15;
  int row_b = (lane >> 4) * 4;
  #pragma unroll
  for (int mt = 0; mt < 4; ++mt)
    #pragma unroll
    for (int nt = 0; nt < 4; ++nt)
      #pragma unroll
      for (int r = 0; r < 4; ++r) {
        int m = m0 + mw + mt * 16 + row_b + r;
        if (m < M)
          C[(size_t)m * N + n0 + nw + nt * 16 + col_l] = f2bf(acc[mt][nt][r]);
      }
}

// ---------- fallback GEMM (fp32-or-bf16 A via VGPR staging) — round-4 kernel ----------
#define GST 40
__global__ __launch_bounds__(256, 2) void bgcn_gemm128(
    const void* __restrict__ Araw, int a_probe, const int* __restrict__ flags,
    const unsigned short* __restrict__ Bt,
    unsigned short* __restrict__ C,
    int M, int N, int K, int nblk_bits) {
  __shared__ unsigned short Abuf[128 * GST];
  __shared__ unsigned short Bbuf[128 * GST];
  const bool a_fp32 = a_probe && flags[0];
  int t = threadIdx.x;
  int wave = t >> 6, lane = t & 63;
  int bx = blockIdx.x;
  int nblk = bx & ((1 << nblk_bits) - 1);
  int mblk = bx >> nblk_bits;
  int m0 = mblk * 128, n0 = nblk * 128;

  floatx4 acc[4][4];
  #pragma unroll
  for (int i = 0; i < 4; ++i)
    #pragma unroll
    for (int j = 0; j < 4; ++j)
      #pragma unroll
      for (int r = 0; r < 4; ++r) acc[i][j][r] = 0.0f;

  int srow  = t >> 1;
  int skoff = (t & 1) * 16;
  int am = m0 + srow; if (am >= M) am = M - 1;
  const float*          Af = (const float*)Araw          + (size_t)am * K + skoff;
  const unsigned short* Ah = (const unsigned short*)Araw + (size_t)am * K + skoff;
  const unsigned short* Bp = Bt + (size_t)(n0 + srow) * K + skoff;
  unsigned short* AL = Abuf + srow * GST + skoff;
  unsigned short* BL = Bbuf + srow * GST + skoff;

  int fr = lane & 15;
  int fk = (lane >> 4) * 8;
  int mw = (wave & 1) * 64;
  int nw = (wave >> 1) * 64;

  for (int k0 = 0; k0 < K; k0 += 32) {
    uint4 a0, a1;
    if (a_fp32) {
      float4 f0 = *(const float4*)(Af + k0);
      float4 f1 = *(const float4*)(Af + k0 + 4);
      float4 f2 = *(const float4*)(Af + k0 + 8);
      float4 f3 = *(const float4*)(Af + k0 + 12);
      a0 = make_uint4(pack2bf(f0.x, f0.y), pack2bf(f0.z, f0.w),
                      pack2bf(f1.x, f1.y), pack2bf(f1.z, f1.w));
      a1 = make_uint4(pack2bf(f2.x, f2.y), pack2bf(f2.z, f2.w),
                      pack2bf(f3.x, f3.y), pack2bf(f3.z, f3.w));
    } else {
      a0 = *(const uint4*)(Ah + k0);
      a1 = *(const uint4*)(Ah + k0 + 8);
    }
    uint4 b0 = *(const uint4*)(Bp + k0);
    uint4 b1 = *(const uint4*)(Bp + k0 + 8);
    *(uint4*)AL       = a0;
    *(uint4*)(AL + 8) = a1;
    *(uint4*)BL       = b0;
    *(uint4*)(BL + 8) = b1;
    __syncthreads();

    short8 afr[4], bfr[4];
    #pragma unroll
    for (int i = 0; i < 4; ++i)
      afr[i] = *(const short8*)(Abuf + (mw + i * 16 + fr) * GST + fk);
    #pragma unroll
    for (int i = 0; i < 4; ++i)
      bfr[i] = *(const short8*)(Bbuf + (nw + i * 16 + fr) * GST + fk);
    #pragma unroll
    for (int mt = 0; mt < 4; ++mt)
      #pragma unroll
      for (int nt = 0; nt < 4; ++nt)
        acc[mt][nt] = __builtin_amdgcn_mfma_f32_16x16x32_bf16(afr[mt], bfr[nt], acc[mt][nt], 0, 0, 0);
    __syncthreads();
  }

  int col_l = lane & 15;
  int row_b = (lane >> 4) * 4;
  #pragma unroll
  for (int mt = 0; mt < 4; ++mt)
    #pragma unroll
    for (int nt = 0; nt < 4; ++nt)
      #pragma unroll
      for (int r = 0; r < 4; ++r) {
        int m = m0 + mw + mt * 16 + row_b + r;
        if (m < M)
          C[(size_t)m * N + n0 + nw + nt * 16 + col_l] = f2bf(acc[mt][nt][r]);
      }
}

// ---------- aggregation: out[c] = sum_e norm*H[src] + (1/deg_c)*H[c] + b, relu ----------
template <int VPL>
__device__ __forceinline__ void loadbf(const unsigned short* p, float* out) {
  if constexpr (VPL == 8) {
    uint4 v = *(const uint4*)p;
    uint32_t w0 = v.x, w1 = v.y, w2 = v.z, w3 = v.w;
    out[0] = bf2f((unsigned short)(w0 & 0xffff)); out[1] = bf2f((unsigned short)(w0 >> 16));
    out[2] = bf2f((unsigned short)(w1 & 0xffff)); out[3] = bf2f((unsigned short)(w1 >> 16));
    out[4] = bf2f((unsigned short)(w2 & 0xffff)); out[5] = bf2f((unsigned short)(w2 >> 16));
    out[6] = bf2f((unsigned short)(w3 & 0xffff)); out[7] = bf2f((unsigned short)(w3 >> 16));
  } else {
    uint32_t v = *(const uint32_t*)p;
    out[0] = bf2f((unsigned short)(v & 0xffff)); out[1] = bf2f((unsigned short)(v >> 16));
  }
}

template <int F>
__global__ __launch_bounds__(256) void bgcn_aggregate(
    const unsigned short* __restrict__ H,
    const int* __restrict__ rowptr,
    const int* __restrict__ esrc,
    const float* __restrict__ enorm,
    const float* __restrict__ dis,
    const unsigned short* __restrict__ bias,
    unsigned short* __restrict__ Out,
    int n_nodes) {
  constexpr int VPL = F / 64;
  int lane = threadIdx.x & 63;
  int c = blockIdx.x * 4 + (threadIdx.x >> 6);  // one wave per node
  if (c >= n_nodes) return;
  float acc[VPL];
  #pragma unroll
  for (int j = 0; j < VPL; ++j) acc[j] = 0.0f;

  int beg = rowptr[c], end = rowptr[c + 1];
  int e = beg;
  for (; e + 4 <= end; e += 4) {
    int s0 = esrc[e], s1 = esrc[e + 1], s2 = esrc[e + 2], s3 = esrc[e + 3];
    float w0 = enorm[e], w1 = enorm[e + 1], w2 = enorm[e + 2], w3 = enorm[e + 3];
    float v0[VPL], v1[VPL], v2[VPL], v3[VPL];
    loadbf<VPL>(H + (size_t)s0 * F + lane * VPL, v0);
    loadbf<VPL>(H + (size_t)s1 * F + lane * VPL, v1);
    loadbf<VPL>(H + (size_t)s2 * F + lane * VPL, v2);
    loadbf<VPL>(H + (size_t)s3 * F + lane * VPL, v3);
    #pragma unroll
    for (int j = 0; j < VPL; ++j) {
      acc[j] += w0 * v0[j];
      acc[j] += w1 * v1[j];
      acc[j] += w2 * v2[j];
      acc[j] += w3 * v3[j];
    }
  }
  for (; e < end; ++e) {
    int src = esrc[e];
    float w = enorm[e];
    float vals[VPL];
    loadbf<VPL>(H + (size_t)src * F + lane * VPL, vals);
    #pragma unroll
    for (int j = 0; j < VPL; ++j) acc[j] += w * vals[j];
  }
  float ds = dis[c];
  float wself = ds * ds;  // == 1/deg
  float vals[VPL];
  loadbf<VPL>(H + (size_t)c * F + lane * VPL, vals);
  unsigned short ob[VPL];
  #pragma unroll
  for (int j = 0; j < VPL; ++j) {
    float v = acc[j] + wself * vals[j] + bf2f(bias[lane * VPL + j]);
    ob[j] = f2bf(fmaxf(v, 0.0f));
  }
  if constexpr (VPL == 8) {
    uint4 st = make_uint4((uint32_t)ob[0] | ((uint32_t)ob[1] << 16),
                          (uint32_t)ob[2] | ((uint32_t)ob[3] << 16),
                          (uint32_t)ob[4] | ((uint32_t)ob[5] << 16),
                          (uint32_t)ob[6] | ((uint32_t)ob[7] << 16));
    *(uint4*)(Out + (size_t)c * F + lane * VPL) = st;
  } else {
    *(uint32_t*)(Out + (size_t)c * F + lane * VPL) =
        (uint32_t)ob[0] | ((uint32_t)ob[1] << 16);
  }
}

// ---------- FC(128->14) + sigmoid -> FP32 output ----------
__global__ __launch_bounds__(256) void bgcn_fc_sigmoid(
    const unsigned short* __restrict__ X,
    const unsigned short* __restrict__ W,
    const unsigned short* __restrict__ b,
    float* __restrict__ out,
    int n_nodes) {
  __shared__ float Ws[128 * 14];
  __shared__ float bs[14];
  for (int i = threadIdx.x; i < 128 * 14; i += 256) Ws[i] = bf2f(W[i]);
  if (threadIdx.x < 14) bs[threadIdx.x] = bf2f(b[threadIdx.x]);
  __syncthreads();
  int node = blockIdx.x * 256 + threadIdx.x;
  if (node >= n_nodes) return;
  float acc[14];
  #pragma unroll
  for (int c = 0; c < 14; ++c) acc[c] = bs[c];
  const unsigned short* xp = X + (size_t)node * 128;
  for (int k8 = 0; k8 < 16; ++k8) {
    float xv[8];
    loadbf<8>(xp + k8 * 8, xv);
    #pragma unroll
    for (int j = 0; j < 8; ++j) {
      int k = k8 * 8 + j;
      #pragma unroll
      for (int c = 0; c < 14; ++c) acc[c] = fmaf(xv[j], Ws[k * 14 + c], acc[c]);
    }
  }
  float* op = out + (size_t)node * 14;
  #pragma unroll
  for (int c = 0; c < 14; ++c)
    op[c] = 1.0f / (1.0f + __expf(-acc[c]));
}

// ---------- launch ----------
static inline size_t padsz(size_t x) { return (x + 255) & ~(size_t)255; }
static inline void* wsa(char*& p, size_t bytes) {
  void* r = p;
  p += padsz(bytes);
  return r;
}

extern "C" void kernel_launch(void* const* d_in, const int* in_sizes, int n_in,
                              void* d_out, int out_size, void* d_ws, size_t ws_size,
                              hipStream_t stream) {
  const void* Xr   = d_in[0];   // [N,1024] fp32 (probed)
  const void* EIr  = d_in[1];   // [2,E] int64 (probed)
  const void* EWr  = d_in[2];   // [E]
  const void* W1r  = d_in[3];   // [1024,512]
  const void* b1r  = d_in[4];
  const void* W2r  = d_in[5];   // [512,128]
  const void* b2r  = d_in[6];
  const void* Wfcr = d_in[7];   // [128,14]
  const void* bfcr = d_in[8];
  float* out = (float*)d_out;   // [N,14] fp32

  const int N = in_sizes[0] / 1024;   // 50000
  const int E = in_sizes[2];          // 800000

  // workspace need for the fast path (X_bf resident)
  size_t need = padsz((size_t)N * 512 * 2)          // R1
              + padsz((size_t)N * 1024 * 2)         // R2 (X_bf / X2)
              + 4 * padsz((size_t)N * 4)            // deg, dis, counts, fill
              + padsz((size_t)(N + 1) * 4)
              + padsz(256 * 4)
              + 2 * padsz((size_t)E * 4)            // esrc, enorm
              + padsz((size_t)2 * E * 4)            // eidx
              + padsz((size_t)E * 2)                // ewb
              + padsz(1024 * 512 * 2) + padsz(512 * 128 * 2)
              + padsz(512 * 2) + padsz(128 * 2) + padsz(128 * 14 * 2)
              + padsz(32) + padsz(8);
  const bool big = ws_size >= need;   // constant across calls -> graph-safe

  char* p = (char*)d_ws;
  unsigned short* R1  = (unsigned short*)wsa(p, (size_t)N * 512 * 2);
  unsigned short* R2  = (unsigned short*)wsa(p, (size_t)N * (big ? 1024 : 512) * 2);
  float* deg      = (float*)wsa(p, (size_t)N * 4);
  float* dis      = (float*)wsa(p, (size_t)N * 4);
  int*   counts   = (int*)wsa(p, (size_t)N * 4);
  int*   fill     = (int*)wsa(p, (size_t)N * 4);
  int*   rowptr   = (int*)wsa(p, (size_t)(N + 1) * 4);
  int*   blocksum = (int*)wsa(p, 256 * 4);
  int*   esrc     = (int*)wsa(p, (size_t)E * 4);
  float* enorm    = (float*)wsa(p, (size_t)E * 4);
  int*   eidx     = (int*)wsa(p, (size_t)2 * E * 4);
  unsigned short* ewb  = (unsigned short*)wsa(p, (size_t)E * 2);
  unsigned short* W1t  = (unsigned short*)wsa(p, (size_t)1024 * 512 * 2);  // [512][1024]
  unsigned short* W2t  = (unsigned short*)wsa(p, (size_t)512 * 128 * 2);   // [128][512]
  unsigned short* b1c  = (unsigned short*)wsa(p, 512 * 2);
  unsigned short* b2c  = (unsigned short*)wsa(p, 128 * 2);
  unsigned short* Wfcc = (unsigned short*)wsa(p, 128 * 14 * 2);
  unsigned short* bfcc = (unsigned short*)wsa(p, 32);
  int* flags      = (int*)wsa(p, 8);

  unsigned short* H1  = R1;                       // [N,512]
  unsigned short* Xbf = R2;                       // [N,1024] (big only)
  unsigned short* X2  = R2;                       // [N,512] — overwrites X_bf (dead)
  unsigned short* H2  = R1;                       // [N,128] — H1 dead
  unsigned short* X3  = R1 + (size_t)N * 128;     // [N,128] — disjoint from H2

  int gN = (N + 255) / 256;
  int gE = (E + 255) / 256;

  // dtype probe + canonicalization
  bgcn_probe<<<1, 64, 0, stream>>>((const uint32_t*)Xr, (const uint32_t*)EIr, flags);
  bgcn_cvt_i<<<(2 * E + 255) / 256, 256, 0, stream>>>(EIr, eidx, 2 * E, flags);
  bgcn_cvt_f<<<gE, 256, 0, stream>>>(EWr, ewb, E, flags);
  bgcn_cvt_t<<<(1024 * 512 + 255) / 256, 256, 0, stream>>>(W1r, W1t, 10, 512, 1024 * 512, flags);
  bgcn_cvt_t<<<(512 * 128 + 255) / 256, 256, 0, stream>>>(W2r, W2t, 9, 128, 512 * 128, flags);
  bgcn_cvt_f<<<2, 256, 0, stream>>>(b1r, b1c, 512, flags);
  bgcn_cvt_f<<<1, 256, 0, stream>>>(b2r, b2c, 128, flags);
  bgcn_cvt_f<<<7, 256, 0, stream>>>(Wfcr, Wfcc, 128 * 14, flags);
  bgcn_cvt_f<<<1, 64, 0, stream>>>(bfcr, bfcc, 14, flags);
  if (big) {
    int n8 = N * 1024 / 8;
    bgcn_cvt8<<<(n8 + 255) / 256, 256, 0, stream>>>(Xr, Xbf, n8, flags);
  }

  const int* rowp = eidx;        // sources
  const int* colp = eidx + E;    // targets

  hipMemsetAsync(counts, 0, (size_t)N * 4, stream);
  hipMemsetAsync(fill,   0, (size_t)N * 4, stream);

  bgcn_init_deg<<<gN, 256, 0, stream>>>(deg, N);
  bgcn_deg<<<gE, 256, 0, stream>>>(colp, ewb, deg, E);
  bgcn_dis<<<gN, 256, 0, stream>>>(deg, dis, N);
  bgcn_hist<<<gE, 256, 0, stream>>>(colp, counts, E);

  int nb = (N + 1023) / 1024;
  bgcn_scan_block<<<nb, 1024, 0, stream>>>(counts, rowptr, blocksum, N);
  bgcn_scan_tops<<<1, 64, 0, stream>>>(blocksum, nb);
  bgcn_scan_add<<<nb, 1024, 0, stream>>>(rowptr, blocksum, N);
  bgcn_scatter<<<gE, 256, 0, stream>>>(rowp, colp, ewb, dis, rowptr, fill, esrc, enorm, E);

  int mblks = (N + 127) / 128;   // 391

  // layer 1: H1 = X @ W1 ; X2 = relu(agg(H1) + b1)
  if (big)
    bgcn_gemm_lds<<<mblks * 4, 256, 0, stream>>>(Xbf, W1t, H1, N, 512, 1024, 2);
  else
    bgcn_gemm128<<<mblks * 4, 256, 0, stream>>>(Xr, 1, flags, W1t, H1, N, 512, 1024, 2);
  bgcn_aggregate<512><<<(N + 3) / 4, 256, 0, stream>>>(H1, rowptr, esrc, enorm, dis, b1c, X2, N);

  // layer 2: H2 = X2 @ W2 ; X3 = relu(agg(H2) + b2)
  bgcn_gemm_lds<<<mblks, 256, 0, stream>>>(X2, W2t, H2, N, 128, 512, 0);
  bgcn_aggregate<128><<<(N + 3) / 4, 256, 0, stream>>>(H2, rowptr, esrc, enorm, dis, b2c, X3, N);

  // FC + sigmoid (fp32 out)
  bgcn_fc_sigmoid<<<gN, 256, 0, stream>>>(X3, Wfcc, bfcc, out, N);
}

// Round 6
// 742.605 us; speedup vs baseline: 1.0515x; 1.0515x over previous
//
#include <hip/hip_runtime.h>
#include <stdint.h>

// ---------- bf16 helpers (OCP bf16 == high 16 bits of f32) ----------
__device__ __forceinline__ float bf2f(unsigned short h) {
  union { uint32_t u; float f; } v; v.u = ((uint32_t)h) << 16; return v.f;
}
__device__ __forceinline__ unsigned short f2bf(float f) {
  union { float f; uint32_t u; } v; v.f = f;
  uint32_t u = v.u;
  u += 0x7FFFu + ((u >> 16) & 1u);   // round-to-nearest-even
  return (unsigned short)(u >> 16);
}
__device__ __forceinline__ uint32_t pack2bf(float a, float b) {
  return (uint32_t)f2bf(a) | ((uint32_t)f2bf(b) << 16);
}
// raw-dtype readers (probed at runtime)
__device__ __forceinline__ int ld_idx(const void* p, size_t i, int is64) {
  return is64 ? (int)((const long long*)p)[i] : ((const int*)p)[i];
}
__device__ __forceinline__ float ld_w(const void* p, size_t i, int f32) {
  return f32 ? ((const float*)p)[i] : bf2f(((const unsigned short*)p)[i]);
}

typedef __attribute__((ext_vector_type(8))) short short8;   // 8 bf16 (4 VGPRs)
typedef __attribute__((ext_vector_type(4))) float floatx4;  // MFMA C/D

// async global->LDS, 16 B/lane. LDS dest = wave-uniform base + lane*16 (m104/m108).
__device__ __forceinline__ void gl2lds16(const unsigned short* g, unsigned short* l) {
  __builtin_amdgcn_global_load_lds(
      (const __attribute__((address_space(1))) uint32_t*)(const void*)g,
      (__attribute__((address_space(3))) uint32_t*)(void*)l,
      16, 0, 0);
}

// ---------- dtype probe ----------
__global__ void bgcn_probe(const uint32_t* __restrict__ xw,
                           const uint32_t* __restrict__ iw,
                           int* __restrict__ flags) {
  if (threadIdx.x == 0 && blockIdx.x == 0) {
    int hits = 0;
    for (int i = 0; i < 256; ++i) {
      uint32_t b = (xw[i] >> 8) & 0x7F;
      if (b >= 0x38 && b <= 0x41) hits++;
    }
    flags[0] = (hits < 128) ? 1 : 0;   // 1 => fp32 floats
    int nz = 0;
    for (int i = 1; i < 128; i += 2) nz += (iw[i] != 0);
    flags[1] = (nz == 0) ? 1 : 0;      // 1 => int64 indices
  }
}

// ---------- canonicalization ----------
// X pre-pass, 8 elem/thread
__global__ void bgcn_cvt8(const void* __restrict__ src, unsigned short* __restrict__ dst,
                          int n8, const int* __restrict__ flags) {
  int i = blockIdx.x * 256 + threadIdx.x;
  if (i >= n8) return;
  size_t o = (size_t)i * 8;
  uint4 d;
  if (flags[0]) {
    const float4* f = (const float4*)((const float*)src + o);
    float4 f0 = f[0], f1 = f[1];
    d = make_uint4(pack2bf(f0.x, f0.y), pack2bf(f0.z, f0.w),
                   pack2bf(f1.x, f1.y), pack2bf(f1.z, f1.w));
  } else {
    d = *(const uint4*)((const unsigned short*)src + o);
  }
  *(uint4*)(dst + o) = d;
}
// LDS-tiled transpose+cvt: dst[N][K] bf16 <- src[K][N]. K,N multiples of 32.
__global__ __launch_bounds__(256) void bgcn_cvt_t(
    const void* __restrict__ src, unsigned short* __restrict__ dst,
    int K, int N, const int* __restrict__ flags) {
  __shared__ unsigned short tile[32][33];
  int k0 = blockIdx.x * 32, n0 = blockIdx.y * 32;
  int tx = threadIdx.x & 31, ty = threadIdx.x >> 5;   // ty 0..7
  bool f32 = flags[0];
  #pragma unroll
  for (int i = 0; i < 4; ++i) {
    size_t s = (size_t)(k0 + ty + i * 8) * N + n0 + tx;
    tile[ty + i * 8][tx] = f32 ? f2bf(((const float*)src)[s])
                               : ((const unsigned short*)src)[s];
  }
  __syncthreads();
  #pragma unroll
  for (int i = 0; i < 4; ++i)
    dst[(size_t)(n0 + ty + i * 8) * K + k0 + tx] = tile[tx][ty + i * 8];
}
// fused small-weight cvt: b1(512) b2(128) Wfc(1792) bfc(14)
__global__ void bgcn_cvt_small(const void* b1, const void* b2,
                               const void* wfc, const void* bfc,
                               unsigned short* db1, unsigned short* db2,
                               unsigned short* dwfc, unsigned short* dbfc,
                               const int* __restrict__ flags) {
  int i = blockIdx.x * 256 + threadIdx.x;
  bool f32 = flags[0];
  const void* s; unsigned short* d; int j;
  if (i < 512)            { s = b1;  d = db1;  j = i; }
  else if (i < 640)       { s = b2;  d = db2;  j = i - 512; }
  else if (i < 2432)      { s = wfc; d = dwfc; j = i - 640; }
  else if (i < 2446)      { s = bfc; d = dbfc; j = i - 2432; }
  else return;
  d[j] = f32 ? f2bf(((const float*)s)[j]) : ((const unsigned short*)s)[j];
}

// ---------- graph preprocessing ----------
__global__ void bgcn_init(float* __restrict__ deg, int* __restrict__ counts,
                          int* __restrict__ fill, int n) {
  int i = blockIdx.x * 256 + threadIdx.x;
  if (i < n) { deg[i] = 1.0f; counts[i] = 0; fill[i] = 0; }
}
__global__ void bgcn_deg_hist(const void* __restrict__ ei, const void* __restrict__ ew,
                              const int* __restrict__ flags,
                              float* __restrict__ deg, int* __restrict__ counts, int E) {
  int e = blockIdx.x * 256 + threadIdx.x;
  if (e >= E) return;
  int c = ld_idx(ei, (size_t)E + e, flags[1]);
  atomicAdd(&deg[c], ld_w(ew, e, flags[0]));
  atomicAdd(&counts[c], 1);
}
__global__ void bgcn_dis(const float* __restrict__ deg, float* __restrict__ dis, int n) {
  int i = blockIdx.x * 256 + threadIdx.x;
  if (i < n) dis[i] = rsqrtf(deg[i]);
}
__global__ void bgcn_scan_block(const int* __restrict__ counts, int* __restrict__ rowptr,
                                int* __restrict__ blocksum, int n) {
  __shared__ int buf[1024];
  int gid = blockIdx.x * 1024 + threadIdx.x;
  int v = (gid < n) ? counts[gid] : 0;
  buf[threadIdx.x] = v;
  __syncthreads();
  for (int off = 1; off < 1024; off <<= 1) {
    int x = (threadIdx.x >= off) ? buf[threadIdx.x - off] : 0;
    __syncthreads();
    buf[threadIdx.x] += x;
    __syncthreads();
  }
  if (gid < n) rowptr[gid + 1] = buf[threadIdx.x];
  if (threadIdx.x == 1023) blocksum[blockIdx.x] = buf[1023];
}
__global__ void bgcn_scan_tops(int* __restrict__ blocksum, int nb) {
  if (threadIdx.x == 0 && blockIdx.x == 0) {
    int acc = 0;
    for (int i = 0; i < nb; ++i) { int v = blocksum[i]; blocksum[i] = acc; acc += v; }
  }
}
__global__ void bgcn_scan_add(int* __restrict__ rowptr, const int* __restrict__ blocksum, int n) {
  int gid = blockIdx.x * 1024 + threadIdx.x;
  if (gid < n) rowptr[gid + 1] += blocksum[blockIdx.x];
  if (gid == 0) rowptr[0] = 0;
}
__global__ void bgcn_scatter(const void* __restrict__ ei, const void* __restrict__ ew,
                             const int* __restrict__ flags,
                             const float* __restrict__ dis,
                             const int* __restrict__ rowptr, int* __restrict__ fill,
                             int* __restrict__ esrc, float* __restrict__ enorm, int E) {
  int e = blockIdx.x * 256 + threadIdx.x;
  if (e >= E) return;
  int is64 = flags[1];
  int r = ld_idx(ei, e, is64), c = ld_idx(ei, (size_t)E + e, is64);
  int pos = rowptr[c] + atomicAdd(&fill[c], 1);
  esrc[pos]  = r;
  enorm[pos] = dis[r] * ld_w(ew, e, flags[0]) * dis[c];
}

// ---------- m97-style MFMA GEMM (bf16 A): C[MxN] = A[MxK] @ Bt[NxK]^T ----------
__global__ __launch_bounds__(256) void bgcn_gemm_lds(
    const unsigned short* __restrict__ A,
    const unsigned short* __restrict__ Bt,
    unsigned short* __restrict__ C,
    int M, int N, int K, int nblk_bits) {
  __shared__ unsigned short Abuf[128 * 32];
  __shared__ unsigned short Bbuf[128 * 32];
  int t = threadIdx.x;
  int wave = t >> 6, lane = t & 63;
  int bx = blockIdx.x;
  int nblk = bx & ((1 << nblk_bits) - 1);
  int mblk = bx >> nblk_bits;
  int m0 = mblk * 128, n0 = nblk * 128;

  floatx4 acc[4][4];
  #pragma unroll
  for (int i = 0; i < 4; ++i)
    #pragma unroll
    for (int j = 0; j < 4; ++j)
      #pragma unroll
      for (int r = 0; r < 4; ++r) acc[i][j][r] = 0.0f;

  int rii  = lane >> 2;
  int koff = (lane & 3) * 8;
  int ar0 = m0 + wave * 32 + rii;      if (ar0 >= M) ar0 = M - 1;
  int ar1 = m0 + wave * 32 + 16 + rii; if (ar1 >= M) ar1 = M - 1;
  const unsigned short* Ag0 = A + (size_t)ar0 * K + koff;
  const unsigned short* Ag1 = A + (size_t)ar1 * K + koff;
  const unsigned short* Bg0 = Bt + (size_t)(n0 + wave * 32 + rii) * K + koff;
  const unsigned short* Bg1 = Bg0 + (size_t)16 * K;
  unsigned short* Al0 = Abuf + (wave * 32) * 32 + lane * 8;
  unsigned short* Al1 = Abuf + (wave * 32 + 16) * 32 + lane * 8;
  unsigned short* Bl0 = Bbuf + (wave * 32) * 32 + lane * 8;
  unsigned short* Bl1 = Bbuf + (wave * 32 + 16) * 32 + lane * 8;

  int fr = lane & 15;
  int fk = (lane >> 4) * 8;
  int mw = (wave & 1) * 64;
  int nw = (wave >> 1) * 64;

  for (int k0 = 0; k0 < K; k0 += 32) {
    gl2lds16(Ag0 + k0, Al0);
    gl2lds16(Ag1 + k0, Al1);
    gl2lds16(Bg0 + k0, Bl0);
    gl2lds16(Bg1 + k0, Bl1);
    __syncthreads();

    short8 afr[4], bfr[4];
    #pragma unroll
    for (int i = 0; i < 4; ++i)
      afr[i] = *(const short8*)(Abuf + (mw + i * 16 + fr) * 32 + fk);
    #pragma unroll
    for (int i = 0; i < 4; ++i)
      bfr[i] = *(const short8*)(Bbuf + (nw + i * 16 + fr) * 32 + fk);
    #pragma unroll
    for (int mt = 0; mt < 4; ++mt)
      #pragma unroll
      for (int nt = 0; nt < 4; ++nt)
        acc[mt][nt] = __builtin_amdgcn_mfma_f32_16x16x32_bf16(afr[mt], bfr[nt], acc[mt][nt], 0, 0, 0);
    __syncthreads();
  }

  int col_l = lane & 15;
  int row_b = (lane >> 4) * 4;
  #pragma unroll
  for (int mt = 0; mt < 4; ++mt)
    #pragma unroll
    for (int nt = 0; nt < 4; ++nt)
      #pragma unroll
      for (int r = 0; r < 4; ++r) {
        int m = m0 + mw + mt * 16 + row_b + r;
        if (m < M)
          C[(size_t)m * N + n0 + nw + nt * 16 + col_l] = f2bf(acc[mt][nt][r]);
      }
}

// ---------- fallback GEMM (fp32-or-bf16 A via VGPR staging) ----------
#define GST 40
__global__ __launch_bounds__(256, 2) void bgcn_gemm128(
    const void* __restrict__ Araw, int a_probe, const int* __restrict__ flags,
    const unsigned short* __restrict__ Bt,
    unsigned short* __restrict__ C,
    int M, int N, int K, int nblk_bits) {
  __shared__ unsigned short Abuf[128 * GST];
  __shared__ unsigned short Bbuf[128 * GST];
  const bool a_fp32 = a_probe && flags[0];
  int t = threadIdx.x;
  int wave = t >> 6, lane = t & 63;
  int bx = blockIdx.x;
  int nblk = bx & ((1 << nblk_bits) - 1);
  int mblk = bx >> nblk_bits;
  int m0 = mblk * 128, n0 = nblk * 128;

  floatx4 acc[4][4];
  #pragma unroll
  for (int i = 0; i < 4; ++i)
    #pragma unroll
    for (int j = 0; j < 4; ++j)
      #pragma unroll
      for (int r = 0; r < 4; ++r) acc[i][j][r] = 0.0f;

  int srow  = t >> 1;
  int skoff = (t & 1) * 16;
  int am = m0 + srow; if (am >= M) am = M - 1;
  const float*          Af = (const float*)Araw          + (size_t)am * K + skoff;
  const unsigned short* Ah = (const unsigned short*)Araw + (size_t)am * K + skoff;
  const unsigned short* Bp = Bt + (size_t)(n0 + srow) * K + skoff;
  unsigned short* AL = Abuf + srow * GST + skoff;
  unsigned short* BL = Bbuf + srow * GST + skoff;

  int fr = lane & 15;
  int fk = (lane >> 4) * 8;
  int mw = (wave & 1) * 64;
  int nw = (wave >> 1) * 64;

  for (int k0 = 0; k0 < K; k0 += 32) {
    uint4 a0, a1;
    if (a_fp32) {
      float4 f0 = *(const float4*)(Af + k0);
      float4 f1 = *(const float4*)(Af + k0 + 4);
      float4 f2 = *(const float4*)(Af + k0 + 8);
      float4 f3 = *(const float4*)(Af + k0 + 12);
      a0 = make_uint4(pack2bf(f0.x, f0.y), pack2bf(f0.z, f0.w),
                      pack2bf(f1.x, f1.y), pack2bf(f1.z, f1.w));
      a1 = make_uint4(pack2bf(f2.x, f2.y), pack2bf(f2.z, f2.w),
                      pack2bf(f3.x, f3.y), pack2bf(f3.z, f3.w));
    } else {
      a0 = *(const uint4*)(Ah + k0);
      a1 = *(const uint4*)(Ah + k0 + 8);
    }
    uint4 b0 = *(const uint4*)(Bp + k0);
    uint4 b1 = *(const uint4*)(Bp + k0 + 8);
    *(uint4*)AL       = a0;
    *(uint4*)(AL + 8) = a1;
    *(uint4*)BL       = b0;
    *(uint4*)(BL + 8) = b1;
    __syncthreads();

    short8 afr[4], bfr[4];
    #pragma unroll
    for (int i = 0; i < 4; ++i)
      afr[i] = *(const short8*)(Abuf + (mw + i * 16 + fr) * GST + fk);
    #pragma unroll
    for (int i = 0; i < 4; ++i)
      bfr[i] = *(const short8*)(Bbuf + (nw + i * 16 + fr) * GST + fk);
    #pragma unroll
    for (int mt = 0; mt < 4; ++mt)
      #pragma unroll
      for (int nt = 0; nt < 4; ++nt)
        acc[mt][nt] = __builtin_amdgcn_mfma_f32_16x16x32_bf16(afr[mt], bfr[nt], acc[mt][nt], 0, 0, 0);
    __syncthreads();
  }

  int col_l = lane & 15;
  int row_b = (lane >> 4) * 4;
  #pragma unroll
  for (int mt = 0; mt < 4; ++mt)
    #pragma unroll
    for (int nt = 0; nt < 4; ++nt)
      #pragma unroll
      for (int r = 0; r < 4; ++r) {
        int m = m0 + mw + mt * 16 + row_b + r;
        if (m < M)
          C[(size_t)m * N + n0 + nw + nt * 16 + col_l] = f2bf(acc[mt][nt][r]);
      }
}

// ---------- aggregation: out[c] = sum_e norm*H[src] + (1/deg_c)*H[c] + b, relu ----------
// 8-wide predicated gather: every iteration keeps 8 row-reads in flight.
__device__ __forceinline__ void accum8(float* acc, uint4 r, float w) {
  acc[0] += w * bf2f((unsigned short)(r.x & 0xffff));
  acc[1] += w * bf2f((unsigned short)(r.x >> 16));
  acc[2] += w * bf2f((unsigned short)(r.y & 0xffff));
  acc[3] += w * bf2f((unsigned short)(r.y >> 16));
  acc[4] += w * bf2f((unsigned short)(r.z & 0xffff));
  acc[5] += w * bf2f((unsigned short)(r.z >> 16));
  acc[6] += w * bf2f((unsigned short)(r.w & 0xffff));
  acc[7] += w * bf2f((unsigned short)(r.w >> 16));
}
__device__ __forceinline__ void accum2(float* acc, uint32_t r, float w) {
  acc[0] += w * bf2f((unsigned short)(r & 0xffff));
  acc[1] += w * bf2f((unsigned short)(r >> 16));
}

template <int F>
__global__ __launch_bounds__(256) void bgcn_aggregate(
    const unsigned short* __restrict__ H,
    const int* __restrict__ rowptr,
    const int* __restrict__ esrc,
    const float* __restrict__ enorm,
    const float* __restrict__ dis,
    const unsigned short* __restrict__ bias,
    unsigned short* __restrict__ Out,
    int n_nodes) {
  constexpr int VPL = F / 64;
  int lane = threadIdx.x & 63;
  int c = blockIdx.x * 4 + (threadIdx.x >> 6);  // one wave per node
  if (c >= n_nodes) return;
  float acc[VPL];
  #pragma unroll
  for (int j = 0; j < VPL; ++j) acc[j] = 0.0f;

  int beg = rowptr[c], end = rowptr[c + 1];
  const unsigned short* Hl = H + (size_t)lane * VPL;

  if (end > beg) {
    for (int e = beg; e < end; e += 8) {
      int   s[8]; float w[8];
      #pragma unroll
      for (int q = 0; q < 8; ++q) {
        int idx = e + q;
        int ii  = idx < end ? idx : end - 1;       // clamped (valid) address
        s[q] = esrc[ii];
        w[q] = idx < end ? enorm[ii] : 0.0f;       // masked weight
      }
      if constexpr (VPL == 8) {
        uint4 r[8];
        #pragma unroll
        for (int q = 0; q < 8; ++q) r[q] = *(const uint4*)(Hl + (size_t)s[q] * F);
        #pragma unroll
        for (int q = 0; q < 8; ++q) accum8(acc, r[q], w[q]);
      } else {
        uint32_t r[8];
        #pragma unroll
        for (int q = 0; q < 8; ++q) r[q] = *(const uint32_t*)(Hl + (size_t)s[q] * F);
        #pragma unroll
        for (int q = 0; q < 8; ++q) accum2(acc, r[q], w[q]);
      }
    }
  }

  float ds = dis[c];
  float wself = ds * ds;  // == 1/deg
  if constexpr (VPL == 8) {
    uint4 rs = *(const uint4*)(Hl + (size_t)c * F);
    accum8(acc, rs, wself);
  } else {
    uint32_t rs = *(const uint32_t*)(Hl + (size_t)c * F);
    accum2(acc, rs, wself);
  }

  unsigned short ob[VPL];
  #pragma unroll
  for (int j = 0; j < VPL; ++j) {
    float v = acc[j] + bf2f(bias[lane * VPL + j]);
    ob[j] = f2bf(fmaxf(v, 0.0f));
  }
  if constexpr (VPL == 8) {
    uint4 st = make_uint4((uint32_t)ob[0] | ((uint32_t)ob[1] << 16),
                          (uint32_t)ob[2] | ((uint32_t)ob[3] << 16),
                          (uint32_t)ob[4] | ((uint32_t)ob[5] << 16),
                          (uint32_t)ob[6] | ((uint32_t)ob[7] << 16));
    *(uint4*)(Out + (size_t)c * F + lane * VPL) = st;
  } else {
    *(uint32_t*)(Out + (size_t)c * F + lane * VPL) =
        (uint32_t)ob[0] | ((uint32_t)ob[1] << 16);
  }
}

// ---------- FC(128->14) + sigmoid -> FP32 output ----------
__global__ __launch_bounds__(256) void bgcn_fc_sigmoid(
    const unsigned short* __restrict__ X,
    const unsigned short* __restrict__ W,
    const unsigned short* __restrict__ b,
    float* __restrict__ out,
    int n_nodes) {
  __shared__ float Ws[128 * 14];
  __shared__ float bs[14];
  for (int i = threadIdx.x; i < 128 * 14; i += 256) Ws[i] = bf2f(W[i]);
  if (threadIdx.x < 14) bs[threadIdx.x] = bf2f(b[threadIdx.x]);
  __syncthreads();
  int node = blockIdx.x * 256 + threadIdx.x;
  if (node >= n_nodes) return;
  float acc[14];
  #pragma unroll
  for (int c = 0; c < 14; ++c) acc[c] = bs[c];
  const unsigned short* xp = X + (size_t)node * 128;
  for (int k8 = 0; k8 < 16; ++k8) {
    uint4 r = *(const uint4*)(xp + k8 * 8);
    float xv[8];
    xv[0] = bf2f((unsigned short)(r.x & 0xffff)); xv[1] = bf2f((unsigned short)(r.x >> 16));
    xv[2] = bf2f((unsigned short)(r.y & 0xffff)); xv[3] = bf2f((unsigned short)(r.y >> 16));
    xv[4] = bf2f((unsigned short)(r.z & 0xffff)); xv[5] = bf2f((unsigned short)(r.z >> 16));
    xv[6] = bf2f((unsigned short)(r.w & 0xffff)); xv[7] = bf2f((unsigned short)(r.w >> 16));
    #pragma unroll
    for (int j = 0; j < 8; ++j) {
      int k = k8 * 8 + j;
      #pragma unroll
      for (int c = 0; c < 14; ++c) acc[c] = fmaf(xv[j], Ws[k * 14 + c], acc[c]);
    }
  }
  float* op = out + (size_t)node * 14;
  #pragma unroll
  for (int c = 0; c < 14; ++c)
    op[c] = 1.0f / (1.0f + __expf(-acc[c]));
}

// ---------- launch ----------
static inline size_t padsz(size_t x) { return (x + 255) & ~(size_t)255; }
static inline void* wsa(char*& p, size_t bytes) {
  void* r = p;
  p += padsz(bytes);
  return r;
}

extern "C" void kernel_launch(void* const* d_in, const int* in_sizes, int n_in,
                              void* d_out, int out_size, void* d_ws, size_t ws_size,
                              hipStream_t stream) {
  const void* Xr   = d_in[0];   // [N,1024] fp32 (probed)
  const void* EIr  = d_in[1];   // [2,E] int64 (probed)
  const void* EWr  = d_in[2];   // [E]
  const void* W1r  = d_in[3];   // [1024,512]
  const void* b1r  = d_in[4];
  const void* W2r  = d_in[5];   // [512,128]
  const void* b2r  = d_in[6];
  const void* Wfcr = d_in[7];   // [128,14]
  const void* bfcr = d_in[8];
  float* out = (float*)d_out;   // [N,14] fp32

  const int N = in_sizes[0] / 1024;   // 50000
  const int E = in_sizes[2];          // 800000

  size_t need = padsz((size_t)N * 512 * 2)          // R1
              + padsz((size_t)N * 1024 * 2)         // R2 (X_bf / X2)
              + 4 * padsz((size_t)N * 4)            // deg, dis, counts, fill
              + padsz((size_t)(N + 1) * 4)
              + padsz(256 * 4)
              + 2 * padsz((size_t)E * 4)            // esrc, enorm
              + padsz(1024 * 512 * 2) + padsz(512 * 128 * 2)
              + padsz(512 * 2) + padsz(128 * 2) + padsz(128 * 14 * 2)
              + padsz(32) + padsz(8);
  const bool big = ws_size >= need;   // constant across calls -> graph-safe

  char* p = (char*)d_ws;
  unsigned short* R1  = (unsigned short*)wsa(p, (size_t)N * 512 * 2);
  unsigned short* R2  = (unsigned short*)wsa(p, (size_t)N * (big ? 1024 : 512) * 2);
  float* deg      = (float*)wsa(p, (size_t)N * 4);
  float* dis      = (float*)wsa(p, (size_t)N * 4);
  int*   counts   = (int*)wsa(p, (size_t)N * 4);
  int*   fill     = (int*)wsa(p, (size_t)N * 4);
  int*   rowptr   = (int*)wsa(p, (size_t)(N + 1) * 4);
  int*   blocksum = (int*)wsa(p, 256 * 4);
  int*   esrc     = (int*)wsa(p, (size_t)E * 4);
  float* enorm    = (float*)wsa(p, (size_t)E * 4);
  unsigned short* W1t  = (unsigned short*)wsa(p, (size_t)1024 * 512 * 2);  // [512][1024]
  unsigned short* W2t  = (unsigned short*)wsa(p, (size_t)512 * 128 * 2);   // [128][512]
  unsigned short* b1c  = (unsigned short*)wsa(p, 512 * 2);
  unsigned short* b2c  = (unsigned short*)wsa(p, 128 * 2);
  unsigned short* Wfcc = (unsigned short*)wsa(p, 128 * 14 * 2);
  unsigned short* bfcc = (unsigned short*)wsa(p, 32);
  int* flags      = (int*)wsa(p, 8);

  unsigned short* H1  = R1;                       // [N,512]
  unsigned short* Xbf = R2;                       // [N,1024] (big only)
  unsigned short* X2  = R2;                       // [N,512] — overwrites X_bf (dead)
  unsigned short* H2  = R1;                       // [N,128] — H1 dead
  unsigned short* X3  = R1 + (size_t)N * 128;     // [N,128] — disjoint from H2

  int gN = (N + 255) / 256;
  int gE = (E + 255) / 256;

  // probe + canonicalize (weights transposed to [N][K] bf16 via LDS tiles)
  bgcn_probe<<<1, 64, 0, stream>>>((const uint32_t*)Xr, (const uint32_t*)EIr, flags);
  { dim3 g(1024 / 32, 512 / 32); bgcn_cvt_t<<<g, 256, 0, stream>>>(W1r, W1t, 1024, 512, flags); }
  { dim3 g(512 / 32, 128 / 32);  bgcn_cvt_t<<<g, 256, 0, stream>>>(W2r, W2t, 512, 128, flags); }
  bgcn_cvt_small<<<10, 256, 0, stream>>>(b1r, b2r, Wfcr, bfcr, b1c, b2c, Wfcc, bfcc, flags);
  if (big) {
    int n8 = N * 1024 / 8;
    bgcn_cvt8<<<(n8 + 255) / 256, 256, 0, stream>>>(Xr, Xbf, n8, flags);
  }

  // graph preprocessing (raw ei/ew, one edge pass for deg+hist)
  bgcn_init<<<gN, 256, 0, stream>>>(deg, counts, fill, N);
  bgcn_deg_hist<<<gE, 256, 0, stream>>>(EIr, EWr, flags, deg, counts, E);
  bgcn_dis<<<gN, 256, 0, stream>>>(deg, dis, N);
  int nb = (N + 1023) / 1024;
  bgcn_scan_block<<<nb, 1024, 0, stream>>>(counts, rowptr, blocksum, N);
  bgcn_scan_tops<<<1, 64, 0, stream>>>(blocksum, nb);
  bgcn_scan_add<<<nb, 1024, 0, stream>>>(rowptr, blocksum, N);
  bgcn_scatter<<<gE, 256, 0, stream>>>(EIr, EWr, flags, dis, rowptr, fill, esrc, enorm, E);

  int mblks = (N + 127) / 128;   // 391

  // layer 1: H1 = X @ W1 ; X2 = relu(agg(H1) + b1)
  if (big)
    bgcn_gemm_lds<<<mblks * 4, 256, 0, stream>>>(Xbf, W1t, H1, N, 512, 1024, 2);
  else
    bgcn_gemm128<<<mblks * 4, 256, 0, stream>>>(Xr, 1, flags, W1t, H1, N, 512, 1024, 2);
  bgcn_aggregate<512><<<(N + 3) / 4, 256, 0, stream>>>(H1, rowptr, esrc, enorm, dis, b1c, X2, N);

  // layer 2: H2 = X2 @ W2 ; X3 = relu(agg(H2) + b2)
  bgcn_gemm_lds<<<mblks, 256, 0, stream>>>(X2, W2t, H2, N, 128, 512, 0);
  bgcn_aggregate<128><<<(N + 3) / 4, 256, 0, stream>>>(H2, rowptr, esrc, enorm, dis, b2c, X3, N);

  // FC + sigmoid (fp32 out)
  bgcn_fc_sigmoid<<<gN, 256, 0, stream>>>(X3, Wfcc, bfcc, out, N);
}